// Round 1
// 1831.924 us; speedup vs baseline: 1.9389x; 1.9389x over previous
//
#include <hip/hip_runtime.h>

#define DFEAT 32
#define SCAN_CHUNK 1024   // elements per scan chunk (256 threads x 4)
#define VPG 4             // vertices per 8-lane gather group

// ===================== Path A: counting-sort + gather =====================
// Avoids all fp32 feature atomics (the measured bottleneck: 192M atomic RMWs
// -> 3.19 GB HBM write traffic at 17% BW). Builds CSR (counts + prefix +
// permutation) with cheap int atomics on L2-resident 4MB arrays, then gathers.

// --- 1. histogram of vertex ids ---
__global__ void he2v_hist(const int* __restrict__ ids,
                          int* __restrict__ counts, int n_he) {
    long tid = (long)blockIdx.x * blockDim.x + threadIdx.x;
    long stride = (long)gridDim.x * blockDim.x;
    long n4 = n_he >> 2;
    for (long t = tid; t < n4; t += stride) {
        int4 w = ((const int4*)ids)[t];
        atomicAdd(&counts[w.x], 1);
        atomicAdd(&counts[w.y], 1);
        atomicAdd(&counts[w.z], 1);
        atomicAdd(&counts[w.w], 1);
    }
    int rem = n_he & 3;
    if (tid < rem) atomicAdd(&counts[ids[(n4 << 2) + tid]], 1);
}

// --- 2a. per-chunk totals ---
__global__ void he2v_chunk_reduce(const int* __restrict__ counts,
                                  int* __restrict__ chunkSums, int n_v) {
    int b = blockIdx.x, t = threadIdx.x;
    int idx = b * SCAN_CHUNK + t * 4;
    int s = 0;
    if (idx + 3 < n_v) {
        int4 c = *(const int4*)(counts + idx);
        s = c.x + c.y + c.z + c.w;
    } else {
        for (int j = 0; j < 4; ++j)
            if (idx + j < n_v) s += counts[idx + j];
    }
    for (int off = 32; off; off >>= 1) s += __shfl_down(s, off, 64);
    __shared__ int ws[4];
    if ((t & 63) == 0) ws[t >> 6] = s;
    __syncthreads();
    if (t == 0) chunkSums[b] = ws[0] + ws[1] + ws[2] + ws[3];
}

// --- 2b. exclusive scan of chunk totals (single block, serial over tiles) ---
__global__ void he2v_scan_chunks(int* __restrict__ cs, int n) {
    __shared__ int buf[1024];
    __shared__ int carry_s;
    int t = threadIdx.x;
    if (t == 0) carry_s = 0;
    __syncthreads();
    for (int base = 0; base < n; base += 1024) {
        int i = base + t;
        int v = (i < n) ? cs[i] : 0;
        buf[t] = v;
        __syncthreads();
        for (int off = 1; off < 1024; off <<= 1) {
            int tv = (t >= off) ? buf[t - off] : 0;
            __syncthreads();
            buf[t] += tv;
            __syncthreads();
        }
        int incl = buf[t];
        int carry = carry_s;
        __syncthreads();                 // everyone has read carry_s
        if (i < n) cs[i] = carry + incl - v;   // exclusive prefix
        if (t == 1023) carry_s = carry + incl; // carry += tile total
        __syncthreads();
    }
}

// --- 2c. apply: cursor[v] = global exclusive prefix of counts ---
__global__ void he2v_scan_apply(const int* __restrict__ counts,
                                const int* __restrict__ chunkExcl,
                                int* __restrict__ cursor, int n_v) {
    int b = blockIdx.x, t = threadIdx.x;
    int idx = b * SCAN_CHUNK + t * 4;
    int c0 = 0, c1 = 0, c2 = 0, c3 = 0;
    if (idx + 3 < n_v) {
        int4 c = *(const int4*)(counts + idx);
        c0 = c.x; c1 = c.y; c2 = c.z; c3 = c.w;
    } else {
        if (idx     < n_v) c0 = counts[idx];
        if (idx + 1 < n_v) c1 = counts[idx + 1];
        if (idx + 2 < n_v) c2 = counts[idx + 2];
        if (idx + 3 < n_v) c3 = counts[idx + 3];
    }
    int s = c0 + c1 + c2 + c3;
    __shared__ int sb[256];
    sb[t] = s;
    __syncthreads();
    for (int off = 1; off < 256; off <<= 1) {
        int v = (t >= off) ? sb[t - off] : 0;
        __syncthreads();
        sb[t] += v;
        __syncthreads();
    }
    int base = chunkExcl[b] + sb[t] - s;
    if (idx     < n_v) cursor[idx]     = base; base += c0;
    if (idx + 1 < n_v) cursor[idx + 1] = base; base += c1;
    if (idx + 2 < n_v) cursor[idx + 2] = base; base += c2;
    if (idx + 3 < n_v) cursor[idx + 3] = base;
}

// --- 3. build permutation: perm[slot] = half-edge index ---
__global__ void he2v_perm_build(const int* __restrict__ ids,
                                int* __restrict__ cursor,
                                int* __restrict__ perm, int n_he) {
    long tid = (long)blockIdx.x * blockDim.x + threadIdx.x;
    long stride = (long)gridDim.x * blockDim.x;
    long n4 = n_he >> 2;
    for (long t = tid; t < n4; t += stride) {
        int4 w = ((const int4*)ids)[t];
        int i0 = (int)(t << 2);
        int p;
        p = atomicAdd(&cursor[w.x], 1); perm[p] = i0;
        p = atomicAdd(&cursor[w.y], 1); perm[p] = i0 + 1;
        p = atomicAdd(&cursor[w.z], 1); perm[p] = i0 + 2;
        p = atomicAdd(&cursor[w.w], 1); perm[p] = i0 + 3;
    }
    int rem = n_he & 3;
    if (tid < rem) {
        int i = (int)(n4 << 2) + (int)tid;
        int p = atomicAdd(&cursor[ids[i]], 1);
        perm[p] = i;
    }
}

// --- 4. gather + divide: 8 lanes per vertex, VPG vertices per group ---
// Each group of 8 lanes reads one half-edge row as 8 consecutive float4s
// (one coalesced 128B segment), accumulates in registers, writes out once.
__global__ void he2v_gather(const float* __restrict__ x,
                            const int* __restrict__ counts,
                            const int* __restrict__ cursor,
                            const int* __restrict__ perm,
                            float* __restrict__ out, int n_v) {
    long tid = (long)blockIdx.x * blockDim.x + threadIdx.x;
    long group = tid >> 3;
    int q = (int)(tid & 7);
    long v0 = group * VPG;
    if (v0 >= n_v) return;
    const float4* x4 = (const float4*)x;
    float4* out4 = (float4*)out;
    for (int vv = 0; vv < VPG; ++vv) {
        long v = v0 + vv;
        if (v >= n_v) break;
        int c = counts[v];
        int base = cursor[v] - c;  // cursor has advanced to end of segment
        float4 acc = make_float4(0.f, 0.f, 0.f, 0.f);
        for (int k = 0; k < c; ++k) {
            int he = perm[base + k];
            float4 xv = x4[(long)he * 8 + q];
            acc.x += xv.x; acc.y += xv.y; acc.z += xv.z; acc.w += xv.w;
        }
        float inv = 1.0f / (float)(c > 0 ? c : 1);
        float4 o;
        o.x = acc.x * inv; o.y = acc.y * inv;
        o.z = acc.z * inv; o.w = acc.w * inv;
        out4[v * 8 + q] = o;
    }
}

// ===================== Path B: fallback (proven atomic scatter) ===========
__global__ void he2v_scatter(const float* __restrict__ x,
                             const int* __restrict__ ids,
                             float* __restrict__ out,
                             float* __restrict__ val,
                             int n_he) {
    long tid = (long)blockIdx.x * blockDim.x + threadIdx.x;
    long stride = (long)gridDim.x * blockDim.x;
    long total = (long)n_he * 8;
    for (long t = tid; t < total; t += stride) {
        int row = (int)(t >> 3);
        int q   = (int)(t & 7);
        int v   = ids[row];
        float4 xv = ((const float4*)x)[(long)row * 8 + q];
        float* dst = out + (long)v * DFEAT + q * 4;
        atomicAdd(dst + 0, xv.x);
        atomicAdd(dst + 1, xv.y);
        atomicAdd(dst + 2, xv.z);
        atomicAdd(dst + 3, xv.w);
        if (q == 0) atomicAdd(val + v, 1.0f);
    }
}

__global__ void he2v_divide(float* __restrict__ out,
                            const float* __restrict__ val,
                            int n_v) {
    long tid = (long)blockIdx.x * blockDim.x + threadIdx.x;
    long total = (long)n_v * 8;
    if (tid >= total) return;
    int v = (int)(tid >> 3);
    float s = val[v];
    if (s < 1.0f) s = 1.0f;
    float4 o = ((float4*)out)[tid];
    o.x /= s; o.y /= s; o.z /= s; o.w /= s;
    ((float4*)out)[tid] = o;
}

extern "C" void kernel_launch(void* const* d_in, const int* in_sizes, int n_in,
                              void* d_out, int out_size, void* d_ws, size_t ws_size,
                              hipStream_t stream) {
    const float* x  = (const float*)d_in[0];
    const int* ids  = (const int*)d_in[1];
    int n_he = in_sizes[0] / DFEAT;
    int n_v  = out_size / DFEAT;
    float* out = (float*)d_out;

    int nchunks = (n_v + SCAN_CHUNK - 1) / SCAN_CHUNK;
    int ncp = (nchunks + 3) & ~3;  // pad for 16B alignment of next array
    size_t need = ((size_t)2 * n_v + (size_t)ncp + (size_t)n_he) * sizeof(int);

    if (ws_size >= need) {
        // ws layout: counts[n_v] | chunkSums[ncp] | cursor[n_v] | perm[n_he]
        int* counts    = (int*)d_ws;
        int* chunkSums = counts + n_v;
        int* cursor    = chunkSums + ncp;
        int* perm      = cursor + n_v;

        hipMemsetAsync(counts, 0, (size_t)n_v * sizeof(int), stream);
        he2v_hist<<<2048, 256, 0, stream>>>(ids, counts, n_he);
        he2v_chunk_reduce<<<nchunks, 256, 0, stream>>>(counts, chunkSums, n_v);
        he2v_scan_chunks<<<1, 1024, 0, stream>>>(chunkSums, nchunks);
        he2v_scan_apply<<<nchunks, 256, 0, stream>>>(counts, chunkSums, cursor, n_v);
        he2v_perm_build<<<4096, 256, 0, stream>>>(ids, cursor, perm, n_he);

        long groups = ((long)n_v + VPG - 1) / VPG;
        long threads = groups * 8;
        int blocks = (int)((threads + 255) / 256);
        he2v_gather<<<blocks, 256, 0, stream>>>(x, counts, cursor, perm, out, n_v);
    } else {
        // Fallback: original atomic-scatter path (needs only n_v floats of ws)
        float* val = (float*)d_ws;
        hipMemsetAsync(out, 0, (size_t)out_size * sizeof(float), stream);
        hipMemsetAsync(val, 0, (size_t)n_v * sizeof(float), stream);
        he2v_scatter<<<8192, 256, 0, stream>>>(x, ids, out, val, n_he);
        long total = (long)n_v * 8;
        int blocks = (int)((total + 255) / 256);
        he2v_divide<<<blocks, 256, 0, stream>>>(out, val, n_v);
    }
}